// Round 2
// baseline (629.046 us; speedup 1.0000x reference)
//
#include <hip/hip_runtime.h>
#include <stdint.h>

#define B_ 8
#define L_ 2500
#define D_ 512
#define Y_ 8921
#define LP 2560   // padded L = 20*128
#define YP 8960   // padded Y = 70*128
#define BLK 128
#define BK 32
#define NKT 16    // 512/32
#define NS 4      // l-splits (blocks along L)
#define LTS 5     // l-tiles of 128 per split (20/NS)
#define TOT (LTS * NKT)   // 80 pipeline steps per block

typedef float f32x16 __attribute__((ext_vector_type(16)));
typedef __bf16 bf16x8 __attribute__((ext_vector_type(8)));
typedef unsigned short u16;
typedef unsigned int u32;

// ---- f32 -> bf16 (RTNE) pack helpers ----
__device__ __forceinline__ u32 pack2(float a, float b) {
  u32 ua = __float_as_uint(a); ua = (ua + 0x7FFFu + ((ua >> 16) & 1u)) >> 16;
  u32 ub = __float_as_uint(b); ub = (ub + 0x7FFFu + ((ub >> 16) & 1u)) >> 16;
  return ua | (ub << 16);
}

// x [B,L,D] f32 -> [B,LP,D] bf16 (pad rows zero)
__global__ void cvt_x_kernel(const float* __restrict__ x, u16* __restrict__ xb) {
  int idx = blockIdx.x * 256 + threadIdx.x;   // one 8-elem chunk
  int row = idx >> 6;                         // b*LP + l
  int c8  = (idx & 63) << 3;
  int b = row / LP;
  int l = row - b * LP;
  uint4 o;
  if (l < L_) {
    const float* s = x + (size_t)(b * L_ + l) * D_ + c8;
    float4 f0 = *(const float4*)s;
    float4 f1 = *(const float4*)(s + 4);
    o.x = pack2(f0.x, f0.y); o.y = pack2(f0.z, f0.w);
    o.z = pack2(f1.x, f1.y); o.w = pack2(f1.z, f1.w);
  } else {
    o = make_uint4(0u, 0u, 0u, 0u);
  }
  *(uint4*)(xb + (size_t)row * D_ + c8) = o;
}

// U,Wf [Y,D] f32 -> [YP,D] bf16 each (pad rows zero)
__global__ void cvt_w_kernel(const float* __restrict__ U, const float* __restrict__ Wf,
                             u16* __restrict__ Ub, u16* __restrict__ Wb) {
  int idx = blockIdx.x * 256 + threadIdx.x;
  const int half = YP * 64;
  const float* src = U; u16* dst = Ub;
  int i = idx;
  if (idx >= half) { i -= half; src = Wf; dst = Wb; }
  int row = i >> 6;
  int c8  = (i & 63) << 3;
  uint4 o;
  if (row < Y_) {
    const float* s = src + (size_t)row * D_ + c8;
    float4 f0 = *(const float4*)s;
    float4 f1 = *(const float4*)(s + 4);
    o.x = pack2(f0.x, f0.y); o.y = pack2(f0.z, f0.w);
    o.z = pack2(f1.x, f1.y); o.w = pack2(f1.z, f1.w);
  } else {
    o = make_uint4(0u, 0u, 0u, 0u);
  }
  *(uint4*)(dst + (size_t)row * D_ + c8) = o;
}

__device__ __forceinline__ void async16(const u16* g, u16* l) {
  __builtin_amdgcn_global_load_lds(
      (const __attribute__((address_space(1))) u32*)g,
      (__attribute__((address_space(3))) u32*)l, 16, 0, 0);
}

// Fused per (y-tile 128, b, l-split): stream LTS l-tiles of 128, MFMA att & s
// with 32x32x16 bf16 MFMA (2382 TF pipe ceiling vs 2075 for 16x16).
//
// LDS tiles are [128 rows][32 k] bf16 with a T2 XOR-swizzle: 16B chunk at row r,
// position p holds k-chunk p ^ ((r>>1)&3). Staging pre-swizzles the GLOBAL source
// column (global_load_lds writes linearly - rule: both-sides-or-neither); reads
// apply the same XOR as a per-lane constant. Kills the 4 cy/read bank conflict.
//
// Partial layout: part[((b*70 + yt)*NS + s)*384 + {0,128,256} + ylocal]
__global__ __launch_bounds__(256, 2) void fused_kernel(
    const u16* __restrict__ xb,   // [B][LP][D] bf16
    const u16* __restrict__ Ub,   // [YP][D]
    const u16* __restrict__ Wb,   // [YP][D]
    float* __restrict__ part)
{
  __shared__ __align__(16) u16 sU[2][BLK * BK];
  __shared__ __align__(16) u16 sW[2][BLK * BK];
  __shared__ __align__(16) u16 sX[2][BLK * BK];

  const int t    = threadIdx.x;
  const int lane = t & 63;
  const int wv   = t >> 6;          // wave 0..3, owns y rows [wv*32, wv*32+32)
  const int r5   = lane & 31;       // MFMA row/col index within 32
  const int hi   = lane >> 5;       // k-half selector within operand
  // swizzled read offset (u16 units): chunk' = (h*2+hi) ^ ((row>>1)&3); h=0 term:
  const int swz  = ((hi ^ ((lane >> 1) & 3)) << 3);   // h=1 offset = swz ^ 16
  const int b    = blockIdx.y;
  const int y0   = blockIdx.x * BLK;
  const int s    = blockIdx.z;      // l-split

  // staging: thread t covers row = t>>2 (+64 for 2nd half). LDS dest is LINEAR
  // (t*16B); the global source column is pre-swizzled so the read-side XOR finds
  // the right k-chunk: src chunk = (t&3) ^ ((row>>1)&3) = (t&3) ^ ((t>>3)&3).
  const int srow = t >> 2;
  const int scol = (((t & 3) ^ ((t >> 3) & 3)) << 3);
  const u16* gU0 = Ub + (size_t)(y0 + srow) * D_ + scol;
  const u16* gU1 = gU0 + (size_t)64 * D_;
  const u16* gW0 = Wb + (size_t)(y0 + srow) * D_ + scol;
  const u16* gW1 = gW0 + (size_t)64 * D_;
  const u16* gXb = xb + (size_t)b * LP * D_ + (size_t)srow * D_ + scol;

  // PER-LANE running softmax stats. 32x32 C/D layout: col(l) = lane&31,
  // row(y) = (reg&3) + 8*(reg>>2) + 4*hi. Each lane: 16 y-rows x 4 l-cols.
  float M[16], Z[16], W[16];
#pragma unroll
  for (int i = 0; i < 16; ++i) { M[i] = -1e30f; Z[i] = 0.f; W[i] = 0.f; }

  auto stage = [&](int stp, int bf) {
    const int kt = stp & (NKT - 1);
    const int lt = stp >> 4;
    const int ko = kt * BK;
    const u16* gX = gXb + (size_t)((s * LTS + lt) * BLK) * D_ + ko;
    async16(gU0 + ko, &sU[bf][t * 8]);
    async16(gU1 + ko, &sU[bf][2048 + t * 8]);
    async16(gW0 + ko, &sW[bf][t * 8]);
    async16(gW1 + ko, &sW[bf][2048 + t * 8]);
    async16(gX,                   &sX[bf][t * 8]);
    async16(gX + (size_t)64 * D_, &sX[bf][2048 + t * 8]);
  };

  // prologue: step 0 into buffer 0
  stage(0, 0);

  const int rowA = wv * 32 + r5;    // A-operand row (y) for this lane

  int step = 0;
  for (int ltl = 0; ltl < LTS; ++ltl) {
    f32x16 accA[4], accS[4];
#pragma unroll
    for (int tt = 0; tt < 4; ++tt)
#pragma unroll
      for (int i = 0; i < 16; ++i) { accA[tt][i] = 0.f; accS[tt][i] = 0.f; }

    for (int kt = 0; kt < NKT; ++kt, ++step) {
      const int nstep = step + 1;
      if (nstep < TOT) stage(nstep, nstep & 1);

      // counted wait: this step's 6 loads retired; the 6 just issued stay in
      // flight across the barrier. Only the final step drains fully.
      if (nstep < TOT) asm volatile("s_waitcnt vmcnt(6)" ::: "memory");
      else             asm volatile("s_waitcnt vmcnt(0)" ::: "memory");
      __builtin_amdgcn_s_barrier();          // publish this step's LDS tiles
      asm volatile("" ::: "memory");

      const int cb = step & 1;
      const u16* bU = sU[cb];
      const u16* bW = sW[cb];
      const u16* bX = sX[cb];

      // A-frags: U/W rows [wv*32, +32), k-halves 0/1 (swizzled chunk offsets)
      bf16x8 aU0 = *(const bf16x8*)(const void*)(bU + rowA * BK + swz);
      bf16x8 aU1 = *(const bf16x8*)(const void*)(bU + rowA * BK + (swz ^ 16));
      bf16x8 aW0 = *(const bf16x8*)(const void*)(bW + rowA * BK + swz);
      bf16x8 aW1 = *(const bf16x8*)(const void*)(bW + rowA * BK + (swz ^ 16));
      __builtin_amdgcn_s_setprio(1);
#pragma unroll
      for (int tt = 0; tt < 4; ++tt) {
        const int rowB = tt * 32 + r5;
        bf16x8 x0 = *(const bf16x8*)(const void*)(bX + rowB * BK + swz);
        bf16x8 x1 = *(const bf16x8*)(const void*)(bX + rowB * BK + (swz ^ 16));
        accA[tt] = __builtin_amdgcn_mfma_f32_32x32x16_bf16(aU0, x0, accA[tt], 0, 0, 0);
        accA[tt] = __builtin_amdgcn_mfma_f32_32x32x16_bf16(aU1, x1, accA[tt], 0, 0, 0);
        accS[tt] = __builtin_amdgcn_mfma_f32_32x32x16_bf16(aW0, x0, accS[tt], 0, 0, 0);
        accS[tt] = __builtin_amdgcn_mfma_f32_32x32x16_bf16(aW1, x1, accS[tt], 0, 0, 0);
      }
      __builtin_amdgcn_s_setprio(0);
      asm volatile("" ::: "memory");
      __builtin_amdgcn_s_barrier();          // allow step+2 to overwrite cb
    }

    // per-lane online softmax update. lane's l-columns: l0 + tt*32 + r5
    const int l0 = (s * LTS + ltl) * BLK;
    const bool boundary = (l0 + BLK > L_);   // wave-uniform; 1 of 20 tiles
    const int lcol = l0 + r5;
#pragma unroll
    for (int si = 0; si < 16; ++si) {
      float a[4];
      if (boundary) {
#pragma unroll
        for (int tt = 0; tt < 4; ++tt) {
          float v = accA[tt][si];
          a[tt] = (lcol + tt * 32 >= L_) ? -1e30f : v;
        }
      } else {
#pragma unroll
        for (int tt = 0; tt < 4; ++tt) a[tt] = accA[tt][si];
      }
      const float tmax  = fmaxf(fmaxf(a[0], a[1]), fmaxf(a[2], a[3]));
      const float mnew  = fmaxf(M[si], tmax);
      const float scale = __expf(M[si] - mnew);
      float zl = 0.f, wl = 0.f;
#pragma unroll
      for (int tt = 0; tt < 4; ++tt) {
        float p = __expf(a[tt] - mnew);
        zl += p;
        wl = fmaf(p, accS[tt][si], wl);
      }
      Z[si] = fmaf(Z[si], scale, zl);
      W[si] = fmaf(W[si], scale, wl);
      M[si] = mnew;
    }
  }

  // ONE cross-lane merge over the 32 l-columns (butterfly with exp rescale).
  // Stages 1..16 keep bit5 fixed, so halves (hi) merge independently - correct,
  // since lanes 0-31 and 32-63 hold different y-rows.
#pragma unroll
  for (int si = 0; si < 16; ++si) {
    float M0 = M[si], Z0 = Z[si], W0 = W[si];
#pragma unroll
    for (int st = 1; st <= 16; st <<= 1) {
      const float Mo = __shfl_xor(M0, st);
      const float Zo = __shfl_xor(Z0, st);
      const float Wo = __shfl_xor(W0, st);
      const float mn = fmaxf(M0, Mo);
      const float sa = __expf(M0 - mn);
      const float sb = __expf(Mo - mn);
      Z0 = Z0 * sa + Zo * sb;
      W0 = W0 * sa + Wo * sb;
      M0 = mn;
    }
    M[si] = M0; Z[si] = Z0; W[si] = W0;
  }

  // write partial (M,Z,W) per owned y-row; stats replicated across the 32
  // l-lanes -> r5==0 writes (lanes 0 and 32, one per y-half).
  if (r5 == 0) {
    float* p = part + ((size_t)(b * 70 + blockIdx.x) * NS + s) * 384;
#pragma unroll
    for (int si = 0; si < 16; ++si) {
      const int yl = wv * 32 + (si & 3) + ((si >> 2) << 3) + (hi << 2);
      p[yl]       = M[si];
      p[128 + yl] = Z[si];
      p[256 + yl] = W[si];
    }
  }
}

// Merge NS partials per (b,y); y = W/Z + bias; BCE partial -> atomicAdd.
__global__ void combine_kernel(const float* __restrict__ part,
                               const float* __restrict__ bias,
                               const float* __restrict__ target,
                               float* __restrict__ out) {
  const int idx = blockIdx.x * 256 + threadIdx.x;
  float lpart = 0.f;
  if (idx < B_ * Y_) {
    const int b = idx / Y_;
    const int y = idx - b * Y_;
    const int yt = y >> 7, yl = y & 127;
    const float* p = part + ((size_t)(b * 70 + yt) * NS) * 384 + yl;
    float M = -1e30f;
#pragma unroll
    for (int s2 = 0; s2 < NS; ++s2) M = fmaxf(M, p[s2 * 384]);
    float Z = 0.f, W = 0.f;
#pragma unroll
    for (int s2 = 0; s2 < NS; ++s2) {
      const float e = __expf(p[s2 * 384] - M);
      Z = fmaf(p[s2 * 384 + 128], e, Z);
      W = fmaf(p[s2 * 384 + 256], e, W);
    }
    const float yv = W / Z + bias[y];
    out[idx] = yv;
    const float tg = target[idx];
    lpart = fmaxf(yv, 0.f) - yv * tg + log1pf(__expf(-fabsf(yv)));
  }
  lpart += __shfl_xor(lpart, 1);  lpart += __shfl_xor(lpart, 2);
  lpart += __shfl_xor(lpart, 4);  lpart += __shfl_xor(lpart, 8);
  lpart += __shfl_xor(lpart, 16); lpart += __shfl_xor(lpart, 32);
  if ((threadIdx.x & 63) == 0)
    atomicAdd(out + (size_t)B_ * Y_, lpart * (1.0f / (B_ * Y_)));
}

extern "C" void kernel_launch(void* const* d_in, const int* in_sizes, int n_in,
                              void* d_out, int out_size, void* d_ws, size_t ws_size,
                              hipStream_t stream) {
  const float* x      = (const float*)d_in[0];
  const float* target = (const float*)d_in[1];
  // d_in[2] = text_inputs (unused by reference)
  const float* U      = (const float*)d_in[3];
  const float* Wf     = (const float*)d_in[4];
  const float* bias   = (const float*)d_in[5];
  float* out = (float*)d_out;

  u16* xb = (u16*)d_ws;                      // [B][LP][D]   20.97 MB
  u16* Ub = xb + (size_t)B_ * LP * D_;       // [YP][D]       9.18 MB
  u16* Wb = Ub + (size_t)YP * D_;            // [YP][D]       9.18 MB
  float* part = (float*)(Wb + (size_t)YP * D_);  // [B][70][NS][384] f32  3.44 MB

  hipMemsetAsync(out + (size_t)B_ * Y_, 0, sizeof(float), stream);
  cvt_x_kernel<<<dim3((B_ * LP * 64) / 256), 256, 0, stream>>>(x, xb);
  cvt_w_kernel<<<dim3((2 * YP * 64) / 256), 256, 0, stream>>>(U, Wf, Ub, Wb);
  fused_kernel<<<dim3(YP / BLK, B_, NS), 256, 0, stream>>>(xb, Ub, Wb, part);
  combine_kernel<<<dim3((B_ * Y_ + 255) / 256), 256, 0, stream>>>(part, bias, target, out);
}